// Round 1
// baseline (7376.031 us; speedup 1.0000x reference)
//
#include <hip/hip_runtime.h>
#include <math.h>

#define B_   32
#define L_   512
#define E_   300
#define H_   256
#define T_   4
#define G4H  1024   // 4*H
#define NTOK 16384  // B*L
#define XGLD 2048   // 2 directions * 4H

__device__ __forceinline__ float sigmoidf_(float x) { return 1.0f / (1.0f + expf(-x)); }

// ---------- transpose Whh [1024][256] -> WhhT [256][1024] ----------
__global__ __launch_bounds__(256) void transpose_k(const float* __restrict__ src,
                                                   float* __restrict__ dst) {
  __shared__ float tile[32][33];
  int lx = threadIdx.x & 31;
  int ly = threadIdx.x >> 5;            // 0..7
  int c0 = blockIdx.x * 32;             // k tile
  int r0 = blockIdx.y * 32;             // g tile
#pragma unroll
  for (int i = 0; i < 32; i += 8)
    tile[ly + i][lx] = src[(size_t)(r0 + ly + i) * H_ + c0 + lx];
  __syncthreads();
#pragma unroll
  for (int i = 0; i < 32; i += 8)
    dst[(size_t)(c0 + ly + i) * G4H + r0 + lx] = tile[lx][ly + i];
}

// ---------- stage A: xg[row][d*1024+g] = emb[wid[row]] . Wih_d[g] + b_d[g] ----------
#define BM 64
#define BN 64
#define BK 20
__global__ __launch_bounds__(256) void xproj_kernel(
    const int*   __restrict__ wid,    // [NTOK]
    const float* __restrict__ emb,    // [V][300]
    const float* __restrict__ wih_f,  // [1024][300]
    const float* __restrict__ wih_b,
    const float* __restrict__ b_f,
    const float* __restrict__ b_b,
    float* __restrict__ xg)           // [NTOK][2048]
{
  __shared__ float As[BM][BK + 1];
  __shared__ float Bs[BK][BN];
  __shared__ int   wid_s[BM];

  int tid = threadIdx.x;
  int m0 = blockIdx.y * BM;
  int n0 = blockIdx.x * BN;            // global col 0..2047
  int d  = n0 >> 10;
  const float* wih  = d ? wih_b : wih_f;
  const float* bias = d ? b_b  : b_f;
  int g0 = n0 & 1023;

  if (tid < BM) wid_s[tid] = wid[m0 + tid];
  __syncthreads();

  int lm = tid >> 2;          // 0..63
  int lk = (tid & 3) * 5;     // 0,5,10,15
  int tx = tid & 15, ty = tid >> 4;

  float acc[4][4] = {};

  for (int k0 = 0; k0 < 300; k0 += BK) {
    const float* erow = emb + (size_t)wid_s[lm] * E_ + k0 + lk;
#pragma unroll
    for (int i = 0; i < 5; ++i) As[lm][lk + i] = erow[i];
    const float* wrow = wih + (size_t)(g0 + lm) * E_ + k0 + lk;
#pragma unroll
    for (int i = 0; i < 5; ++i) Bs[lk + i][lm] = wrow[i];
    __syncthreads();
#pragma unroll
    for (int k = 0; k < BK; ++k) {
      float a0 = As[ty * 4 + 0][k], a1 = As[ty * 4 + 1][k];
      float a2 = As[ty * 4 + 2][k], a3 = As[ty * 4 + 3][k];
      float b0 = Bs[k][tx * 4 + 0], b1 = Bs[k][tx * 4 + 1];
      float b2 = Bs[k][tx * 4 + 2], b3 = Bs[k][tx * 4 + 3];
      acc[0][0] += a0 * b0; acc[0][1] += a0 * b1; acc[0][2] += a0 * b2; acc[0][3] += a0 * b3;
      acc[1][0] += a1 * b0; acc[1][1] += a1 * b1; acc[1][2] += a1 * b2; acc[1][3] += a1 * b3;
      acc[2][0] += a2 * b0; acc[2][1] += a2 * b1; acc[2][2] += a2 * b2; acc[2][3] += a2 * b3;
      acc[3][0] += a3 * b0; acc[3][1] += a3 * b1; acc[3][2] += a3 * b2; acc[3][3] += a3 * b3;
    }
    __syncthreads();
  }

#pragma unroll
  for (int i = 0; i < 4; ++i) {
    int row = m0 + ty * 4 + i;
    float* op = xg + (size_t)row * XGLD + n0 + tx * 4;
#pragma unroll
    for (int jj = 0; jj < 4; ++jj)
      op[jj] = acc[i][jj] + bias[g0 + tx * 4 + jj];
  }
}

// ---------- stage B: LSTM recurrence, one block per (dir, batch) ----------
__global__ __launch_bounds__(256) void lstm_kernel(
    const float* __restrict__ xg,    // [NTOK][2048]
    const float* __restrict__ whhT,  // [2][256][1024]  (k-major)
    const float* __restrict__ wout,  // [4][512]
    float* __restrict__ em)          // [2][32][512][4]
{
  int blk = blockIdx.x;              // 0..63
  int d = blk >> 5;
  int b = blk & 31;
  int j = threadIdx.x;               // hidden index 0..255

  const float* WT = whhT + (size_t)d * (H_ * G4H);

  __shared__ float h_lds[H_];

  int wave = j >> 6, lane = j & 63;
  float wo[4];
#pragma unroll
  for (int cc = 0; cc < 4; ++cc)
    wo[cc] = wout[wave * 512 + d * 256 + cc * 64 + lane];

  float c = 0.0f;
  h_lds[j] = 0.0f;
  __syncthreads();

  for (int s = 0; s < L_; ++s) {
    int t = d ? (L_ - 1 - s) : s;
    const float* xgp = xg + ((size_t)(b * L_ + t)) * XGLD + d * G4H;
    float a0 = xgp[j], a1 = xgp[256 + j], a2 = xgp[512 + j], a3 = xgp[768 + j];

#pragma unroll 4
    for (int k = 0; k < H_; ++k) {
      float hk = h_lds[k];
      const float* w = WT + (size_t)k * G4H;
      a0 += hk * w[j];
      a1 += hk * w[256 + j];
      a2 += hk * w[512 + j];
      a3 += hk * w[768 + j];
    }

    float ig = sigmoidf_(a0);
    float fg = sigmoidf_(a1);
    float gg = tanhf(a2);
    float og = sigmoidf_(a3);
    c = fg * c + ig * gg;
    float h = og * tanhf(c);

    __syncthreads();       // all reads of previous h done
    h_lds[j] = h;
    __syncthreads();       // h complete for emission + next step

    // emissions: wave w computes tag w for this direction's half of W_out
    float part = 0.0f;
#pragma unroll
    for (int cc = 0; cc < 4; ++cc)
      part += h_lds[cc * 64 + lane] * wo[cc];
#pragma unroll
    for (int off = 32; off >= 1; off >>= 1)
      part += __shfl_down(part, off, 64);
    if (lane == 0)
      em[(((size_t)(d * 32 + b)) * L_ + t) * 4 + wave] = part;
  }
}

// ---------- Viterbi decode ----------
__global__ __launch_bounds__(64) void viterbi_kernel(
    const float* __restrict__ em,      // [2][32][512][4]
    const float* __restrict__ bout,    // [4]
    const float* __restrict__ trans,   // [4][4]
    const float* __restrict__ strans,  // [4]
    const float* __restrict__ etrans,  // [4]
    const int*   __restrict__ mask,    // [32][512]
    int* __restrict__ hist,            // [32][512][4]
    int* __restrict__ out)             // [32][512]
{
  int b = threadIdx.x;
  if (b >= B_) return;

  const float* emf = em + ((size_t)b * L_) * 4;
  const float* emb2 = em + ((size_t)(B_ + b) * L_) * 4;

  float tr[4][4];
#pragma unroll
  for (int i = 0; i < 4; ++i)
#pragma unroll
    for (int jj = 0; jj < 4; ++jj) tr[i][jj] = trans[i * 4 + jj];
  float bo[4];
#pragma unroll
  for (int i = 0; i < 4; ++i) bo[i] = bout[i];

  float sc[4];
#pragma unroll
  for (int tag = 0; tag < 4; ++tag)
    sc[tag] = strans[tag] + emf[0 * 4 + tag] + emb2[0 * 4 + tag] + bo[tag];

  for (int t = 1; t < L_; ++t) {
    float ns[4];
#pragma unroll
    for (int to = 0; to < 4; ++to) {
      float best = sc[0] + tr[0][to];
      int bf = 0;
#pragma unroll
      for (int fr = 1; fr < 4; ++fr) {
        float v = sc[fr] + tr[fr][to];
        if (v > best) { best = v; bf = fr; }
      }
      ns[to] = best + emf[t * 4 + to] + emb2[t * 4 + to] + bo[to];
      hist[((size_t)b * L_ + t) * 4 + to] = bf;
    }
    int mt = mask[b * L_ + t];
#pragma unroll
    for (int to = 0; to < 4; ++to) sc[to] = mt ? ns[to] : sc[to];
  }

#pragma unroll
  for (int tag = 0; tag < 4; ++tag) sc[tag] += etrans[tag];
  int cur = 0;
  float best = sc[0];
#pragma unroll
  for (int i = 1; i < 4; ++i)
    if (sc[i] > best) { best = sc[i]; cur = i; }

  out[b * L_ + (L_ - 1)] = cur * (mask[b * L_ + (L_ - 1)] ? 1 : 0);
  for (int t = L_ - 1; t >= 1; --t) {
    if (mask[b * L_ + t]) cur = hist[((size_t)b * L_ + t) * 4 + cur];
    out[b * L_ + (t - 1)] = cur * (mask[b * L_ + (t - 1)] ? 1 : 0);
  }
}

extern "C" void kernel_launch(void* const* d_in, const int* in_sizes, int n_in,
                              void* d_out, int out_size, void* d_ws, size_t ws_size,
                              hipStream_t stream) {
  const int*   word_ids = (const int*)d_in[0];
  const int*   mask     = (const int*)d_in[1];
  // d_in[2] label_ids: unused
  const float* emb   = (const float*)d_in[3];
  const float* Wih_f = (const float*)d_in[4];
  const float* Whh_f = (const float*)d_in[5];
  const float* b_f   = (const float*)d_in[6];
  const float* Wih_b = (const float*)d_in[7];
  const float* Whh_b = (const float*)d_in[8];
  const float* b_b   = (const float*)d_in[9];
  const float* W_out = (const float*)d_in[10];
  const float* b_out = (const float*)d_in[11];
  const float* trans = (const float*)d_in[12];
  const float* strans = (const float*)d_in[13];
  const float* etrans = (const float*)d_in[14];
  int* out = (int*)d_out;

  float* xg   = (float*)d_ws;                         // 16384*2048 f32 = 128 MiB
  float* whhT = xg + (size_t)NTOK * XGLD;             // 2*256*1024 f32 = 2 MiB
  float* em   = whhT + (size_t)2 * H_ * G4H;          // 2*32*512*4 f32 = 0.5 MiB
  int*   hist = (int*)(em + (size_t)2 * B_ * L_ * T_);// 32*512*4 i32 = 0.25 MiB

  transpose_k<<<dim3(8, 32), 256, 0, stream>>>(Whh_f, whhT);
  transpose_k<<<dim3(8, 32), 256, 0, stream>>>(Whh_b, whhT + (size_t)H_ * G4H);
  xproj_kernel<<<dim3(32, 256), 256, 0, stream>>>(word_ids, emb, Wih_f, Wih_b, b_f, b_b, xg);
  lstm_kernel<<<64, 256, 0, stream>>>(xg, whhT, W_out, em);
  viterbi_kernel<<<1, 64, 0, stream>>>(em, b_out, trans, strans, etrans, mask, hist, out);
}